// Round 1
// baseline (116.528 us; speedup 1.0000x reference)
//
#include <hip/hip_runtime.h>
#include <hip/hip_bf16.h>
#include <cstdint>

#define B_ROWS 16384
#define K_CODES 4096
#define D_DIM 256

typedef __attribute__((ext_vector_type(8))) short short8;
typedef __attribute__((ext_vector_type(4))) float floatx4;
typedef unsigned long long u64;

__device__ __forceinline__ short f2bf_rne(float f) {
    unsigned u = __float_as_uint(f);
    u = (u + 0x7FFFu + ((u >> 16) & 1u)) >> 16;
    return (short)u;
}

// monotone float->uint map (no NaNs in this problem)
__device__ __forceinline__ unsigned ordf(float f) {
    unsigned u = __float_as_uint(f);
    return (u & 0x80000000u) ? ~u : (u | 0x80000000u);
}

// ---------- kernel 1: w fp32 -> bf16, w_sqr, minkey init ----------
__global__ __launch_bounds__(256) void prep_kernel(
        const float* __restrict__ w, short* __restrict__ wb,
        float* __restrict__ wsq, u64* __restrict__ minkey) {
    const int row = blockIdx.x;      // 0..4095
    const int t = threadIdx.x;       // 0..255
    float v = w[row * D_DIM + t];
    wb[row * D_DIM + t] = f2bf_rne(v);
    float s = v * v;
    for (int m = 1; m < 64; m <<= 1) s += __shfl_xor(s, m, 64);
    __shared__ float part[4];
    const int wave = t >> 6, lane = t & 63;
    if (lane == 0) part[wave] = s;
    __syncthreads();
    if (t == 0) wsq[row] = part[0] + part[1] + part[2] + part[3];
    if (t < 4) minkey[row * 4 + t] = ~0ULL;   // re-init every call (ws is re-poisoned)
}

// ---------- kernel 2: bf16 MFMA score + argmin ----------
// Wave owns 32 rows (2 M-blocks of 16). WG = 4 waves = 128 rows.
// 4-way code split: grid = 128 * 4 = 512 WGs; cross-split merge via atomicMin.
#define NT 64                  // codes per LDS tile
#define LDS_STRIDE 264         // 256 + 8 shorts pad -> 528 B row stride (bank-safe)

__global__ __launch_bounds__(256, 2) void argmin_kernel(
        const float* __restrict__ z, const short* __restrict__ wb,
        const float* __restrict__ wsq, u64* __restrict__ minkey) {
    __shared__ short lds_w[NT * LDS_STRIDE];

    const int rowblk = blockIdx.x & 127;
    const int split  = blockIdx.x >> 7;        // 0..3
    const int wave   = threadIdx.x >> 6;
    const int lane   = threadIdx.x & 63;
    const int lo16   = lane & 15;
    const int q      = lane >> 4;              // 0..3

    const int row_base = rowblk * 128 + wave * 32;

    // Persistent A fragments: A[m = lane&15][k = q*8 + j], 8 k-steps cover D=256
    short8 afrag[2][8];
#pragma unroll
    for (int mb = 0; mb < 2; ++mb) {
        const float* zr = z + (size_t)(row_base + mb * 16 + lo16) * D_DIM + q * 8;
#pragma unroll
        for (int s = 0; s < 8; ++s) {
            floatx4 f0 = *(const floatx4*)(zr + 32 * s);
            floatx4 f1 = *(const floatx4*)(zr + 32 * s + 4);
            short8 a;
            a[0] = f2bf_rne(f0[0]); a[1] = f2bf_rne(f0[1]);
            a[2] = f2bf_rne(f0[2]); a[3] = f2bf_rne(f0[3]);
            a[4] = f2bf_rne(f1[0]); a[5] = f2bf_rne(f1[1]);
            a[6] = f2bf_rne(f1[2]); a[7] = f2bf_rne(f1[3]);
            afrag[mb][s] = a;
        }
    }

    float minv[2][4];
    int   mini[2][4];
#pragma unroll
    for (int mb = 0; mb < 2; ++mb)
#pragma unroll
        for (int j = 0; j < 4; ++j) { minv[mb][j] = INFINITY; mini[mb][j] = 0; }

    const int code_lo = split * (K_CODES / 4);

    for (int tile = 0; tile < (K_CODES / 4) / NT; ++tile) {
        const int code_base = code_lo + tile * NT;
        __syncthreads();
        // stage NT x 256 bf16 tile (16B chunks, 8 per thread)
#pragma unroll
        for (int i = 0; i < 8; ++i) {
            int c  = threadIdx.x + i * 256;    // 0..2047
            int r  = c >> 5;                    // 32 chunks per row
            int c8 = c & 31;
            uint4 v = *(const uint4*)(wb + (size_t)(code_base + r) * D_DIM + c8 * 8);
            *(uint4*)&lds_w[r * LDS_STRIDE + c8 * 8] = v;
        }
        __syncthreads();

#pragma unroll
        for (int nb = 0; nb < 4; ++nb) {
            // B fragment: B[k = q*8+j][n = lane&15] = w[code][d] -> contiguous 16B per lane
            const short* bp = &lds_w[(nb * 16 + lo16) * LDS_STRIDE + q * 8];
            short8 bf[8];
#pragma unroll
            for (int s = 0; s < 8; ++s) bf[s] = *(const short8*)(bp + 32 * s);

            floatx4 acc0 = {0.f, 0.f, 0.f, 0.f};
            floatx4 acc1 = {0.f, 0.f, 0.f, 0.f};
#pragma unroll
            for (int s = 0; s < 8; ++s) {
                acc0 = __builtin_amdgcn_mfma_f32_16x16x32_bf16(afrag[0][s], bf[s], acc0, 0, 0, 0);
                acc1 = __builtin_amdgcn_mfma_f32_16x16x32_bf16(afrag[1][s], bf[s], acc1, 0, 0, 0);
            }
            const int col = code_base + nb * 16 + lo16;
            const float ws = wsq[col];
#pragma unroll
            for (int j = 0; j < 4; ++j) {
                float s0 = fmaf(-2.0f, acc0[j], ws);
                if (s0 < minv[0][j]) { minv[0][j] = s0; mini[0][j] = col; }
                float s1 = fmaf(-2.0f, acc1[j], ws);
                if (s1 < minv[1][j]) { minv[1][j] = s1; mini[1][j] = col; }
            }
        }
    }

    // reduce min across the 16 lanes holding each row; merge splits via atomicMin
#pragma unroll
    for (int mb = 0; mb < 2; ++mb)
#pragma unroll
        for (int j = 0; j < 4; ++j) {
            float v = minv[mb][j];
            int   i = mini[mb][j];
#pragma unroll
            for (int m = 1; m <= 8; m <<= 1) {
                float ov = __shfl_xor(v, m, 64);
                int   oi = __shfl_xor(i, m, 64);
                if (ov < v || (ov == v && oi < i)) { v = ov; i = oi; }
            }
            if (lo16 == 0) {
                int row = row_base + mb * 16 + q * 4 + j;  // C layout: row=(lane>>4)*4+reg
                u64 key = ((u64)ordf(v) << 32) | (unsigned)i;
                atomicMin(&minkey[row], key);
            }
        }
}

// ---------- kernel 3: exact fp32 loss for the selected code ----------
__global__ __launch_bounds__(256) void loss_kernel(
        const float* __restrict__ z, const float* __restrict__ w,
        const u64* __restrict__ minkey, float* __restrict__ out) {
    const int wave = threadIdx.x >> 6, lane = threadIdx.x & 63;
    const int row = blockIdx.x * 4 + wave;
    const unsigned idx = (unsigned)(minkey[row] & 0xFFFFFFFFu);
    floatx4 zv = *(const floatx4*)(z + (size_t)row * D_DIM + lane * 4);
    floatx4 wv = *(const floatx4*)(w + (size_t)idx * D_DIM + lane * 4);
    float d0 = zv[0] - wv[0], d1 = zv[1] - wv[1];
    float d2 = zv[2] - wv[2], d3 = zv[3] - wv[3];
    float s = d0 * d0 + d1 * d1 + d2 * d2 + d3 * d3;
    for (int m = 1; m < 64; m <<= 1) s += __shfl_xor(s, m, 64);
    if (lane == 0) out[row] = 1.25f * s;   // vq + 0.25 * commitment (identical sums)
}

extern "C" void kernel_launch(void* const* d_in, const int* in_sizes, int n_in,
                              void* d_out, int out_size, void* d_ws, size_t ws_size,
                              hipStream_t stream) {
    const float* z = (const float*)d_in[0];
    const float* w = (const float*)d_in[1];
    float* out = (float*)d_out;

    char* ws = (char*)d_ws;
    short* wb    = (short*)ws;                              // 4096*256*2 = 2 MiB
    float* wsq   = (float*)(ws + 2097152);                  // 16 KiB
    u64*   minkey = (u64*)(ws + 2097152 + 16384);           // 128 KiB (8-aligned)

    prep_kernel<<<K_CODES, 256, 0, stream>>>(w, wb, wsq, minkey);
    argmin_kernel<<<512, 256, 0, stream>>>(z, wb, wsq, minkey);
    loss_kernel<<<B_ROWS / 4, 256, 0, stream>>>(z, w, minkey, out);
}